// Round 18
// baseline (3586721.875 us; speedup 1.0000x reference)
//
#include <hip/hip_runtime.h>

// DeepLSTM persistent wavefront pipeline for MI355X (gfx950).
// R18 = R17 with the inline-asm i8-constraint compile fix (value operand
// widened to unsigned int). Design unchanged:
// XCD-local recurrence with RACE-FREE xcc-based role assignment.
// 1 WG/CU x grid 256 => exactly 32 WGs per XCD (architectural guarantee).
// Each WG publishes XCC_ID to a write-once table; all WGs read the SAME
// completed table and deterministically compute (g=xcc, rank=scan-order).
// If table invalid -> all WGs identically fall back to R16's protocol.
// xcc-mode: recurrent edge local (sc0 h + sc0 flag after vmcnt(1) local
// ack; NO in-loop MALL drain); inter-layer fsm posted after the tail
// pre-check (its internal vmcnt(0) doubles as the MALL drain); input panel
// PRELOADED at tail when pre-check succeeds. All polls spin-capped.

constexpr int Tv = 512;
constexpr int Iv = 256;
constexpr int Hv = 512;
constexpr int LAYv = 4;
constexpr int THREADS = 256; // 4 waves; wave w = N-tile
constexpr int NKK = 32;      // K/32 (512 rec + 512 in)
constexpr int WTABH = 4 * NKK * 64 * 8; // shorts, hi table = 128KB
constexpr int SCR_STRIDE = 20;
constexpr unsigned SMEM_BYTES = WTABH * 2 + 4 * 16 * SCR_STRIDE * 4; // 136192
constexpr int SPIN_CAP = 1 << 16; // fail-loud, never hang
constexpr int TAB_CAP = 1 << 22;

typedef short sfrag __attribute__((ext_vector_type(8)));
typedef float facc __attribute__((ext_vector_type(4)));
typedef float f32x4 __attribute__((ext_vector_type(4)));

struct Params {
  const float *x;
  const float *Wx0i, *Wx0f, *Wx0o, *Wx0c;
  const float *Wxi, *Wxf, *Wxo, *Wxc;
  const float *Whi, *Whf, *Who, *Whc;
  const float *bi, *bf, *bo, *bc;
  float *out;
  unsigned short *hmall; // [dmask+1][8 g][16][512] bf16 ring, double-stored
  unsigned char *fsm;    // [512][8 g][32 rank][4 w] bytes (MALL, write-once)
  unsigned short *ffast; // [2][8 g][128] ushort value-coded (local L2)
  unsigned short *fsafe; // [2][8 g][128] ushort value-coded (MALL, fallback)
  unsigned char *xcctab; // [256] xcc+1 per bid, write-once
  int dmask;
};

__device__ __forceinline__ unsigned short f2bf(float f) {
  unsigned int u = __builtin_bit_cast(unsigned int, f);
  u += 0x7FFFu + ((u >> 16) & 1u); // RNE
  return (unsigned short)(u >> 16);
}
__device__ __forceinline__ float bf2f(unsigned short s) {
  unsigned int u = ((unsigned int)s) << 16;
  return __builtin_bit_cast(float, u);
}

// ---- cache-control primitives ----
__device__ __forceinline__ unsigned ld_u32_sc0(const int *p) { // L1-bypass, L2
  unsigned v;
  asm volatile("global_load_dword %0, %1, off sc0\n\ts_waitcnt vmcnt(0)"
               : "=v"(v) : "v"(p) : "memory");
  return v;
}
__device__ __forceinline__ unsigned ld_u32_byp(const int *p) { // full bypass
  unsigned v;
  asm volatile("global_load_dword %0, %1, off sc0 sc1\n\ts_waitcnt vmcnt(0)"
               : "=v"(v) : "v"(p) : "memory");
  return v;
}
__device__ __forceinline__ void st2_short(unsigned short *p, unsigned int v) {
  asm volatile("global_store_short %0, %1, off sc0\n\t"
               "global_store_short %0, %1, off sc0 sc1" ::"v"(p), "v"(v)
               : "memory");
}
__device__ __forceinline__ void st_short_sc0(unsigned short *p, unsigned int v) {
  asm volatile("global_store_short %0, %1, off sc0" ::"v"(p), "v"(v) : "memory");
}
__device__ __forceinline__ void st_short_byp(unsigned short *p, unsigned int v) {
  asm volatile("global_store_short %0, %1, off sc0 sc1" ::"v"(p), "v"(v) : "memory");
}
__device__ __forceinline__ void st_u8_byp(unsigned char *p, unsigned int v) {
  asm volatile("global_store_byte %0, %1, off sc0 sc1" ::"v"(p), "v"(v) : "memory");
}

__global__ void __launch_bounds__(THREADS, 1) lstm_pipeline(Params p) {
  const int bid = blockIdx.x;
  const int tid = threadIdx.x;
  const int lane = tid & 63;
  const int w = tid >> 6; // wave = N-tile
  const int kgrp = lane >> 4;

  extern __shared__ char smem[];
  unsigned short *wlds_hi = (unsigned short *)smem;          // [4][32][64][8]
  float *scratch = (float *)(smem + (size_t)WTABH * 2) +
                   (size_t)w * 16 * SCR_STRIDE;              // wave-private
  __shared__ int shtab[64];
  __shared__ int sh_g, sh_rank, sh_ok;

  // ---- race-free role assignment from the write-once xcc table ----
  if (tid == 0) {
    unsigned xv = 0;
    asm volatile("s_getreg_b32 %0, hwreg(20, 0, 32)" : "=s"(xv)); // XCC_ID
    st_u8_byp(p.xcctab + bid, (xv & 7u) + 1u);
  }
  if (tid < 64) {
    int spin = 0;
    unsigned v;
    for (;;) {
      v = ld_u32_byp((const int *)p.xcctab + tid);
      if (((v & 0xFFu) && (v & 0xFF00u) && (v & 0xFF0000u) && (v & 0xFF000000u)) ||
          ++spin > TAB_CAP)
        break;
      __builtin_amdgcn_s_sleep(4);
    }
    shtab[tid] = (int)v;
  }
  __syncthreads();
  if (tid == 0) {
    const unsigned char *tb = (const unsigned char *)shtab;
    int cnt[8] = {0, 0, 0, 0, 0, 0, 0, 0};
    int okv = 1;
    for (int i = 0; i < 256; ++i) {
      int xv = (int)tb[i] - 1;
      if (xv < 0 || xv > 7) { okv = 0; break; }
      cnt[xv]++;
    }
    if (okv)
      for (int i = 0; i < 8; ++i) okv &= (cnt[i] == 32);
    int rk = 0;
    if (okv)
      for (int i = 0; i < bid; ++i) rk += (tb[i] == tb[bid]);
    sh_ok = okv;
    sh_g = okv ? ((int)tb[bid] - 1) : (bid & 7);
    sh_rank = okv ? rk : (bid >> 3);
  }
  __syncthreads();
  const int ok = sh_ok, g = sh_g, rank = sh_rank;
  const int l = g >> 1, mt = g & 1, gsrc = g - 2;

  // gate-indexed weight bases for this layer
  const float *Wh[4] = {p.Whi + (size_t)l * Hv * Hv, p.Whf + (size_t)l * Hv * Hv,
                        p.Who + (size_t)l * Hv * Hv, p.Whc + (size_t)l * Hv * Hv};
  const float *Wx[4];
  if (l == 0) { Wx[0] = p.Wx0i; Wx[1] = p.Wx0f; Wx[2] = p.Wx0o; Wx[3] = p.Wx0c; }
  else {
    size_t o = (size_t)(l - 1) * Hv * Hv;
    Wx[0] = p.Wxi + o; Wx[1] = p.Wxf + o; Wx[2] = p.Wxo + o; Wx[3] = p.Wxc + o;
  }
  const int kx_max = (l == 0) ? Iv : Hv;

  // ---- stage HI weights into LDS (this WG's 16 units -> 64 gate-cols) ----
  for (int idx = tid; idx < 4 * NKK * 64; idx += THREADS) {
    int lanei = idx & 63;
    int kk = (idx >> 6) & (NKK - 1);
    int nti = idx >> 11;
    int kbase = kk * 32 + (lanei >> 4) * 8;
    int n = nti * 16 + (lanei & 15);
    int u = n >> 2, gg = n & 3;
    int col = rank * 16 + u;
    sfrag vh;
#pragma unroll
    for (int j = 0; j < 8; ++j) {
      int k = kbase + j;
      float wv;
      if (k < Hv) wv = Wh[gg][(size_t)k * Hv + col];
      else { int kx = k - Hv; wv = (kx < kx_max) ? Wx[gg][(size_t)kx * Hv + col] : 0.f; }
      vh[j] = (short)f2bf(wv);
    }
    *(sfrag *)&wlds_hi[(size_t)idx * 8] = vh;
  }
  // ---- stage LO weights into VGPRs ----
  sfrag lov[NKK];
#pragma unroll
  for (int kk = 0; kk < NKK; ++kk) {
    int kbase = kk * 32 + kgrp * 8;
    int n = w * 16 + (lane & 15);
    int u = n >> 2, gg = n & 3;
    int col = rank * 16 + u;
    sfrag vl;
#pragma unroll
    for (int j = 0; j < 8; ++j) {
      int k = kbase + j;
      float wv;
      if (k < Hv) wv = Wh[gg][(size_t)k * Hv + col];
      else { int kx = k - Hv; wv = (kx < kx_max) ? Wx[gg][(size_t)kx * Hv + col] : 0.f; }
      unsigned short h16 = f2bf(wv);
      vl[j] = (short)f2bf(wv - bf2f(h16));
    }
    lov[kk] = vl;
  }

  const int er = lane >> 2, eu = lane & 3;
  const int ju = rank * 16 + w * 4 + eu;
  const float bia_i = p.bi[l * Hv + ju];
  const float bia_f = p.bf[l * Hv + ju];
  const float bia_o = p.bo[l * Hv + ju];
  const float bia_c = p.bc[l * Hv + ju];
  float cst = 0.f;

  __syncthreads(); // weights staged -- only barrier in the loop body scope

  unsigned short *hmall = p.hmall, *ffast = p.ffast, *fsafe = p.fsafe;
  unsigned char *fsm = p.fsm;
  const int dmask = p.dmask;

#define GEMM16(A, KKB)                                                         \
  {                                                                            \
    _Pragma("unroll") for (int j = 0; j < 16; ++j) {                           \
      sfrag bh = *(const sfrag *)&wlds_hi[(size_t)(((w * NKK) + (KKB) + j) * 64 + lane) * 8]; \
      acc0 = __builtin_amdgcn_mfma_f32_16x16x32_bf16(A[j], bh, acc0, 0, 0, 0); \
      acc1 = __builtin_amdgcn_mfma_f32_16x16x32_bf16(A[j], lov[(KKB) + j], acc1, 0, 0, 0); \
    }                                                                          \
  }

  sfrag ain[16];
  bool pre_ok = false;

  for (int t = 0; t < Tv; ++t) {
    facc acc0 = {0.f, 0.f, 0.f, 0.f};
    facc acc1 = {0.f, 0.f, 0.f, 0.f};

    // ================= input half =================
    if (l == 0) {
      const float *xbp =
          p.x + ((size_t)(mt * 16 + (lane & 15)) * Tv + t) * Iv + kgrp * 8;
#pragma unroll
      for (int kk = 0; kk < 8; ++kk) {
        f32x4 lo = *(const f32x4 *)(xbp + kk * 32);
        f32x4 hi = *(const f32x4 *)(xbp + kk * 32 + 4);
        sfrag ax;
#pragma unroll
        for (int j = 0; j < 4; ++j) { ax[j] = (short)f2bf(lo[j]); ax[4 + j] = (short)f2bf(hi[j]); }
        sfrag bh = *(const sfrag *)&wlds_hi[(size_t)(((w * NKK) + 16 + kk) * 64 + lane) * 8];
        acc0 = __builtin_amdgcn_mfma_f32_16x16x32_bf16(ax, bh, acc0, 0, 0, 0);
        acc1 = __builtin_amdgcn_mfma_f32_16x16x32_bf16(ax, lov[16 + kk], acc1, 0, 0, 0);
      }
    } else {
      if (!pre_ok) { // blocking input-edge poll + load
        const int *fb = (const int *)(fsm + ((size_t)t * 8 + gsrc) * 128);
        int spin = 0;
        for (;;) {
          int v = (lane < 32) ? (int)ld_u32_byp(fb + lane) : 0x01010101;
          if (__all(v == 0x01010101) || ++spin > SPIN_CAP) break;
          __builtin_amdgcn_s_sleep(1);
        }
        const unsigned short *hin =
            hmall + (((size_t)((t + 1) & dmask) * 8 + gsrc) * 16 + (lane & 15)) * 512;
#pragma unroll
        for (int kk = 0; kk < 16; ++kk)
          ain[kk] = *(const sfrag *)(hin + kk * 32 + kgrp * 8);
      }
      GEMM16(ain, 16)
    }

    // ================= recurrent half =================
    if (t > 0) {
      if (ok) { // pure-local detect (same-XCD L2)
        const int *pf = (const int *)(ffast + (size_t)((t & 1) * 8 + g) * 128);
        const unsigned exp32 = (unsigned)t * 0x10001u;
        int spin = 0;
        for (;;) {
          unsigned v = ld_u32_sc0(pf + lane);
          if (__all(v == exp32) || ++spin > SPIN_CAP) break;
          __builtin_amdgcn_s_sleep(1);
        }
      } else { // fallback: sc0 fast + every-4th sc1 safe
        const int *pf = (const int *)(ffast + (size_t)((t & 1) * 8 + g) * 128) + lane;
        const int *ps = (const int *)(fsafe + (size_t)((t & 1) * 8 + g) * 128) + lane;
        const unsigned exp32 = (unsigned)t * 0x10001u;
        int spin = 0;
        for (;;) {
          unsigned v = ((spin & 3) == 3) ? ld_u32_byp(ps) : ld_u32_sc0(pf);
          if (__all(v == exp32) || ++spin > SPIN_CAP) break;
          __builtin_amdgcn_s_sleep(1);
        }
      }
      const unsigned short *hrec =
          hmall + (((size_t)(t & dmask) * 8 + g) * 16 + (lane & 15)) * 512;
      sfrag arec[16];
#pragma unroll
      for (int kk = 0; kk < 16; ++kk)
        arec[kk] = *(const sfrag *)(hrec + kk * 32 + kgrp * 8);
      GEMM16(arec, 0)
    } // t==0: h=0 contributes nothing

    // ---- in-wave transpose via wave-private scratch (no barrier) ----
    {
      int rl = (lane >> 4) * 4, cl = lane & 15;
#pragma unroll
      for (int r = 0; r < 4; ++r)
        scratch[(rl + r) * SCR_STRIDE + cl] = acc0[r] + acc1[r];
    }
    f32x4 q = *(const f32x4 *)&scratch[er * SCR_STRIDE + eu * 4];

    // ---- gates / state: one chain per lane ----
    float pi = q[0] + bia_i, pf_ = q[1] + bia_f, po = q[2] + bia_o, pc = q[3] + bia_c;
    float gi = 1.f / (1.f + __expf(-pi));
    float gf = 1.f / (1.f + __expf(-pf_));
    float go = 1.f / (1.f + __expf(-po));
    float gc = tanhf(pc);
    cst = gf * cst + gi * gc;
    float hval = go * tanhf(cst);
    unsigned int hbf = (unsigned int)f2bf(hval);

    // ---- tail ----
    unsigned short *haddr =
        &hmall[(((size_t)((t + 1) & dmask) * 8 + g) * 16 + er) * 512 + ju];
    st2_short(haddr, hbf); // sc0 local copy + sc1 MALL copy
    asm volatile("s_waitcnt vmcnt(1)" ::: "memory"); // local (sc0) h ack'd in L2
    if (lane == 0)
      st_short_sc0(ffast + (size_t)(((t + 1) & 1) * 8 + g) * 128 + rank * 4 + w,
                   (unsigned int)(t + 1));
    if (l == LAYv - 1)
      p.out[((size_t)(mt * 16 + er) * Tv + t) * Hv + ju] = hval;

    if (ok) {
      if (l > 0 && t + 1 < Tv) {
        // pre-check next input flag; its vmcnt(0) doubles as the MALL drain
        const int *fb2 = (const int *)(fsm + ((size_t)(t + 1) * 8 + gsrc) * 128);
        int v = (lane < 32) ? (int)ld_u32_byp(fb2 + lane) : 0x01010101;
        pre_ok = (bool)__all(v == 0x01010101);
        if (l < LAYv - 1 && lane == 0) // h_sc1(t) drained by pre-check vmcnt(0)
          st_u8_byp(fsm + ((size_t)t * 8 + g) * 128 + rank * 4 + w, 1u);
        if (pre_ok) { // preload next input panel (flight overlaps loop-back)
          const unsigned short *hin2 =
              hmall + (((size_t)((t + 2) & dmask) * 8 + gsrc) * 16 + (lane & 15)) * 512;
#pragma unroll
          for (int kk = 0; kk < 16; ++kk)
            ain[kk] = *(const sfrag *)(hin2 + kk * 32 + kgrp * 8);
        }
      } else if (l == 0) {
        // deferred fsm: h slot t (stored at tail t-1) long MALL-ack'd by now
        if (t > 0 && lane == 0)
          st_u8_byp(fsm + ((size_t)(t - 1) * 8 + g) * 128 + rank * 4 + w, 1u);
        pre_ok = false;
      } else {
        pre_ok = false; // l>0, t==511: fsm[511] owed post-loop
      }
    } else {
      // fallback tail (R16): full MALL drain + safe flags every iter
      asm volatile("s_waitcnt vmcnt(0)" ::: "memory");
      if (lane == 0) {
        st_short_byp(fsafe + (size_t)(((t + 1) & 1) * 8 + g) * 128 + rank * 4 + w,
                     (unsigned int)(t + 1));
        if (l < LAYv - 1)
          st_u8_byp(fsm + ((size_t)t * 8 + g) * 128 + rank * 4 + w, 1u);
      }
      pre_ok = false;
    }
  }
  // post-loop: xcc-mode owes the final inter-layer flag (l==0 owes t=511 too)
  if (ok && l < LAYv - 1) {
    asm volatile("s_waitcnt vmcnt(0)" ::: "memory");
    if (lane == 0)
      st_u8_byp(fsm + ((size_t)(Tv - 1) * 8 + g) * 128 + rank * 4 + w, 1u);
  }
#undef GEMM16
}

extern "C" void kernel_launch(void *const *d_in, const int *in_sizes, int n_in,
                              void *d_out, int out_size, void *d_ws, size_t ws_size,
                              hipStream_t stream) {
  Params prm;
  prm.x = (const float *)d_in[0];
  prm.Wx0i = (const float *)d_in[1];
  prm.Wx0f = (const float *)d_in[2];
  prm.Wx0o = (const float *)d_in[3];
  prm.Wx0c = (const float *)d_in[4];
  prm.Wxi = (const float *)d_in[5];
  prm.Wxf = (const float *)d_in[6];
  prm.Wxo = (const float *)d_in[7];
  prm.Wxc = (const float *)d_in[8];
  prm.Whi = (const float *)d_in[9];
  prm.Whf = (const float *)d_in[10];
  prm.Who = (const float *)d_in[11];
  prm.Whc = (const float *)d_in[12];
  prm.bi = (const float *)d_in[13];
  prm.bf = (const float *)d_in[14];
  prm.bo = (const float *)d_in[15];
  prm.bc = (const float *)d_in[16];
  prm.out = (float *)d_out;

  size_t slot_b = (size_t)8 * 16 * 512 * 2; // 128KB per t-slot
  size_t fsm_b = (size_t)512 * 8 * 128;     // 512KB
  size_t ff_b = (size_t)2 * 8 * 128 * 2;    // 4KB each
  size_t tab_b = 256;
  size_t hslots = 512; // read-once ring
  if (ws_size < hslots * slot_b + fsm_b + 2 * ff_b + tab_b) {
    hslots = 256;
    if (ws_size < hslots * slot_b + fsm_b + 2 * ff_b + tab_b) return;
  }
  prm.dmask = (int)hslots - 1;
  char *base = (char *)d_ws;
  prm.hmall = (unsigned short *)base;
  prm.fsm = (unsigned char *)(base + hslots * slot_b);
  prm.ffast = (unsigned short *)(base + hslots * slot_b + fsm_b);
  prm.fsafe = (unsigned short *)(base + hslots * slot_b + fsm_b + ff_b);
  prm.xcctab = (unsigned char *)(base + hslots * slot_b + fsm_b + 2 * ff_b);

  // zero all flags + table (contiguous) every call -- deterministic replays
  hipMemsetAsync(prm.fsm, 0, fsm_b + 2 * ff_b + tab_b, stream);

  hipFuncSetAttribute(reinterpret_cast<const void *>(lstm_pipeline),
                      hipFuncAttributeMaxDynamicSharedMemorySize, (int)SMEM_BYTES);

  // 136KB LDS -> 1 WG/CU; grid 256 == #CUs -> co-resident, 32 WGs/XCD.
  hipLaunchKernelGGL(lstm_pipeline, dim3(256), dim3(THREADS), SMEM_BYTES,
                     stream, prm);
}